// Round 7
// baseline (366.414 us; speedup 1.0000x reference)
//
#include <hip/hip_runtime.h>

typedef __attribute__((ext_vector_type(4))) float    float4v;
typedef __attribute__((ext_vector_type(8))) _Float16 half8v;
typedef __attribute__((ext_vector_type(4))) _Float16 half4v;

// Problem geometry (fixed by reference setup_inputs).
constexpr int B_ = 8;
constexpr int H_ = 480;
constexpr int W_ = 640;
constexpr int HW = H_ * W_;          // 307200
constexpr int N  = B_ * HW;          // 2457600 pixels
constexpr int WPP = 28;              // fp16 weights per pixel (27 + pad, 56 B)

// Fused-2-step tile geometry.
constexpr int TI = 40;               // out tile rows   (480/40 = 12, exact)
constexpr int TJ = 64;               // out tile cols   (640/64 = 10, exact)
constexpr int LR = 52;               // LDS region rows = TI + 12
constexpr int LC = 80;               // LDS region cols = TJ + 16 (pitch, 16B-aligned)
// LDS (li,lj) <-> global (ti0 + li - 6, tj0 + lj - 8)
constexpr int QROWS = 46;            // x1/w ownership rows: [-3, 43)
constexpr int QCOLS = 18;            // ownership quads/row: cols [-4, 68)
constexpr int NOWN  = QROWS * QCOLS; // 828
constexpr int BLK   = 832;           // 13 waves

// ---------------------------------------------------------------------------
// Weight precompute (round-5, proven): packed per-pixel w[p][0..27] fp16.
// ---------------------------------------------------------------------------
__global__ __launch_bounds__(256) void wprep_kernel(
    const float* __restrict__ g1, const float* __restrict__ g2,
    const float* __restrict__ g3, const float* __restrict__ fuse,
    _Float16* __restrict__ w)
{
    const int p  = blockIdx.x * 256 + threadIdx.x;   // pixel id, < N
    const int b  = p / HW;
    const int hw = p - b * HW;

    _Float16 wl[WPP];
    wl[27] = (_Float16)0.f;

    const float* gs[3] = {g1, g2, g3};
#pragma unroll
    for (int d = 0; d < 3; ++d) {
        const float* gb = gs[d] + (size_t)b * 9 * HW + hw;
        float e[9];
        float m = -1e30f;
#pragma unroll
        for (int c = 0; c < 9; ++c) {
            e[c] = gb[(size_t)c * HW];
            m = fmaxf(m, e[c]);
        }
        float s = 0.f;
#pragma unroll
        for (int c = 0; c < 9; ++c) {
            e[c] = __expf(e[c] - m);
            s += e[c];
        }
        const float f = fuse[((size_t)b * 3 + d) * HW + hw] / s;
#pragma unroll
        for (int c = 0; c < 9; ++c)
            wl[d * 9 + c] = (_Float16)(e[c] * f);
    }

    _Float16* wp = w + (size_t)p * WPP;
    *(half8v*)(wp + 0)  = *(half8v*)(wl + 0);
    *(half8v*)(wp + 8)  = *(half8v*)(wl + 8);
    *(half8v*)(wp + 16) = *(half8v*)(wl + 16);
    *(half4v*)(wp + 24) = *(half4v*)(wl + 24);
}

// Select tap t (compile-time after unroll) from a pixel's packed weights.
__device__ __forceinline__ float wsel(const half8v& a, const half8v& b,
                                      const half8v& c, const half4v& d, int t)
{
    if (t < 8)  return (float)a[t];
    if (t < 16) return (float)b[t - 8];
    if (t < 24) return (float)c[t - 16];
    return (float)d[t - 24];
}

// ---------------------------------------------------------------------------
// Fused 2-step propagation. Each block: out tile TIxTJ of one image.
// x0 region (halo 6) -> LDS; each thread owns one 4-px quad of the w-support
// region, keeps its 4x27 fp16 weights in registers across both steps.
// ---------------------------------------------------------------------------
__global__ __launch_bounds__(BLK) void prop2_kernel(
    const float* __restrict__ xin, const _Float16* __restrict__ w,
    float* __restrict__ xout)
{
    __shared__ float xs[LR * LC];                  // 16.6 KB

    const int tid   = threadIdx.x;
    const int tileJ = blockIdx.x;                  // 0..9
    const int tileI = blockIdx.y;                  // 0..11
    const int b     = blockIdx.z;
    const int ti0   = tileI * TI;
    const int tj0   = tileJ * TJ;
    const float* xb = xin + (size_t)b * HW;

    // ---- stage x0 region into LDS (zero-padded outside image) ----
    for (int idx = tid; idx < LR * LC / 4; idx += BLK) {
        const int r   = idx / (LC / 4);            // 0..51
        const int q   = idx % (LC / 4);            // 0..19
        const int gi  = ti0 + r - 6;
        const int gj0 = tj0 + q * 4 - 8;
        float4v v = {0.f, 0.f, 0.f, 0.f};
        if ((unsigned)gi < (unsigned)H_) {
            if (gj0 >= 0 && gj0 + 3 < W_) {
                v = *(const float4v*)(xb + (size_t)gi * W_ + gj0);
            } else {
#pragma unroll
                for (int k = 0; k < 4; ++k) {
                    const int gj = gj0 + k;
                    if ((unsigned)gj < (unsigned)W_) v[k] = xb[(size_t)gi * W_ + gj];
                }
            }
        }
        *(float4v*)&xs[r * LC + q * 4] = v;
    }

    // ---- load the owned quad's weights into registers ----
    const bool owner = (tid < NOWN);
    const int qr  = tid / QCOLS;                   // 0..45
    const int qc  = tid % QCOLS;                   // 0..17
    const int li  = 3 + qr;                        // LDS row of owned px
    const int lj0 = 4 + qc * 4;                    // LDS col of quad start
    const int gi  = ti0 + qr - 3;                  // global row
    const int gj0 = tj0 + qc * 4 - 4;              // global col of quad start

    const half8v z8 = {0, 0, 0, 0, 0, 0, 0, 0};
    const half4v z4 = {0, 0, 0, 0};
    half8v w0[4] = {z8, z8, z8, z8};
    half8v w1[4] = {z8, z8, z8, z8};
    half8v w2[4] = {z8, z8, z8, z8};
    half4v w3[4] = {z4, z4, z4, z4};

    if (owner && (unsigned)gi < (unsigned)H_) {
#pragma unroll
        for (int k = 0; k < 4; ++k) {
            const int gj = gj0 + k;
            if ((unsigned)gj < (unsigned)W_) {
                const _Float16* wp = w + ((size_t)b * HW + (size_t)gi * W_ + gj) * WPP;
                w0[k] = *(const half8v*)(wp + 0);
                w1[k] = *(const half8v*)(wp + 8);
                w2[k] = *(const half8v*)(wp + 16);
                w3[k] = *(const half4v*)(wp + 24);
            }
        }
    }
    __syncthreads();

    // ---- step 1: x1 at every owned px (OOB px have zero weights -> 0) ----
    float x1[4] = {0.f, 0.f, 0.f, 0.f};
    if (owner) {
#pragma unroll
        for (int dd = 0; dd < 3; ++dd) {
            const int d = dd + 1;
#pragma unroll
            for (int ki = 0; ki < 3; ++ki) {
                const int base = (li + (ki - 1) * d) * LC + lj0;
                float win[12];
                *(float4v*)&win[0] = *(const float4v*)&xs[base - 4];
                *(float4v*)&win[4] = *(const float4v*)&xs[base];
                *(float4v*)&win[8] = *(const float4v*)&xs[base + 4];
#pragma unroll
                for (int kj = 0; kj < 3; ++kj) {
                    const int t   = dd * 9 + ki * 3 + kj;
                    const int off = (kj - 1) * d + 4;
#pragma unroll
                    for (int k = 0; k < 4; ++k)
                        x1[k] = fmaf(win[off + k], wsel(w0[k], w1[k], w2[k], w3[k], t), x1[k]);
                }
            }
        }
    }
    __syncthreads();                               // all x0 reads complete

    // ---- write x1 in place over x0 ----
    if (owner) {
        float4v v; v[0] = x1[0]; v[1] = x1[1]; v[2] = x1[2]; v[3] = x1[3];
        *(float4v*)&xs[li * LC + lj0] = v;
    }
    __syncthreads();

    // ---- step 2: x2 only on the out tile (same weights, from registers) ----
    const bool outq = owner && (qr >= 3) && (qr < 3 + TI) && (qc >= 1) && (qc < 17);
    if (outq) {
        float x2[4] = {0.f, 0.f, 0.f, 0.f};
#pragma unroll
        for (int dd = 0; dd < 3; ++dd) {
            const int d = dd + 1;
#pragma unroll
            for (int ki = 0; ki < 3; ++ki) {
                const int base = (li + (ki - 1) * d) * LC + lj0;
                float win[12];
                *(float4v*)&win[0] = *(const float4v*)&xs[base - 4];
                *(float4v*)&win[4] = *(const float4v*)&xs[base];
                *(float4v*)&win[8] = *(const float4v*)&xs[base + 4];
#pragma unroll
                for (int kj = 0; kj < 3; ++kj) {
                    const int t   = dd * 9 + ki * 3 + kj;
                    const int off = (kj - 1) * d + 4;
#pragma unroll
                    for (int k = 0; k < 4; ++k)
                        x2[k] = fmaf(win[off + k], wsel(w0[k], w1[k], w2[k], w3[k], t), x2[k]);
                }
            }
        }
        float4v v; v[0] = x2[0]; v[1] = x2[1]; v[2] = x2[2]; v[3] = x2[3];
        *(float4v*)(xout + (size_t)b * HW + (size_t)gi * W_ + gj0) = v;
    }
}

// ---------------------------------------------------------------------------
extern "C" void kernel_launch(void* const* d_in, const int* in_sizes, int n_in,
                              void* d_out, int out_size, void* d_ws, size_t ws_size,
                              hipStream_t stream)
{
    const float* g1   = (const float*)d_in[0];
    const float* g2   = (const float*)d_in[1];
    const float* g3   = (const float*)d_in[2];
    const float* fuse = (const float*)d_in[3];
    const float* x    = (const float*)d_in[4];
    float* out = (float*)d_out;

    char* ws = (char*)d_ws;
    _Float16* w = (_Float16*)ws;                      // N*28*2 = 137.6 MB
    float* xa = (float*)(ws + (size_t)N * WPP * 2);   // ping
    float* xb = xa + N;                               // pong

    wprep_kernel<<<N / 256, 256, 0, stream>>>(g1, g2, g3, fuse, w);

    const dim3 pgrid(W_ / TJ, H_ / TI, B_);           // 10 x 12 x 8
    // 8 steps = 4 fused launches of 2 steps each.
    prop2_kernel<<<pgrid, BLK, 0, stream>>>(x,  w, xa);
    prop2_kernel<<<pgrid, BLK, 0, stream>>>(xa, w, xb);
    prop2_kernel<<<pgrid, BLK, 0, stream>>>(xb, w, xa);
    prop2_kernel<<<pgrid, BLK, 0, stream>>>(xa, w, out);
}

// Round 8
// 274.272 us; speedup vs baseline: 1.3359x; 1.3359x over previous
//
#include <hip/hip_runtime.h>

// Problem geometry (fixed by reference setup_inputs).
constexpr int B_ = 8;
constexpr int H_ = 480;
constexpr int W_ = 640;
constexpr int HW = H_ * W_;          // 307200
constexpr int N  = B_ * HW;          // 2457600 pixels

// ---------------------------------------------------------------------------
// Fused weight-precompute + propagation pass 1.
// 1 px/thread (round-3 proven layout: wave = 64 consecutive j).
// Per d-group: softmax(guided_d)*fuse_d in fp32 registers -> (a) store fp16
// planar w[27][N] for passes 2..8, (b) apply the 9 taps to x with the exact
// fp32 weights -> x1. Extra cost over plain wprep: 27 mostly-cached x loads
// + one x1 store per pixel.
// ---------------------------------------------------------------------------
__global__ __launch_bounds__(256) void wprep1_kernel(
    const float* __restrict__ g1, const float* __restrict__ g2,
    const float* __restrict__ g3, const float* __restrict__ fuse,
    const float* __restrict__ x,
    _Float16* __restrict__ w, float* __restrict__ x1out)
{
    const int j  = blockIdx.x * 64 + (threadIdx.x & 63);
    const int i  = blockIdx.y * 4  + (threadIdx.x >> 6);
    const int b  = blockIdx.z;
    const int hw = i * W_ + j;
    const int p  = b * HW + hw;

    const float* xb = x + (size_t)b * HW;
    const float* gs[3] = {g1, g2, g3};

    float acc = 0.f;
#pragma unroll
    for (int d = 0; d < 3; ++d) {
        const int dil = d + 1;
        const float* gb = gs[d] + (size_t)b * 9 * HW + hw;

        float e[9];
        float m = -1e30f;
#pragma unroll
        for (int c = 0; c < 9; ++c) {
            e[c] = gb[(size_t)c * HW];
            m = fmaxf(m, e[c]);
        }
        float s = 0.f;
#pragma unroll
        for (int c = 0; c < 9; ++c) {
            e[c] = __expf(e[c] - m);
            s += e[c];
        }
        const float f = fuse[((size_t)b * 3 + d) * HW + hw] / s;

#pragma unroll
        for (int ki = 0; ki < 3; ++ki) {
            const int ii = i + (ki - 1) * dil;
            const bool vi = (unsigned)ii < (unsigned)H_;
#pragma unroll
            for (int kj = 0; kj < 3; ++kj) {
                const int c  = ki * 3 + kj;
                const float wv = e[c] * f;
                w[(size_t)(d * 9 + c) * N + p] = (_Float16)wv;

                const int jj = j + (kj - 1) * dil;
                float xv = 0.f;
                if (vi && (unsigned)jj < (unsigned)W_)
                    xv = xb[ii * W_ + jj];
                acc = fmaf(xv, wv, acc);
            }
        }
    }
    x1out[p] = acc;
}

// ---------------------------------------------------------------------------
// One propagation step (round-3 proven kernel): out[p] = 27-tap x*w, fp16 w.
// 1 pixel/thread; wave covers 64 consecutive j -> all loads coalesced.
// ---------------------------------------------------------------------------
__global__ __launch_bounds__(256) void prop_kernel(
    const float* __restrict__ xin, const _Float16* __restrict__ w,
    float* __restrict__ xout)
{
    const int j  = blockIdx.x * 64 + (threadIdx.x & 63);
    const int i  = blockIdx.y * 4  + (threadIdx.x >> 6);
    const int b  = blockIdx.z;
    const int hw = i * W_ + j;
    const int p  = b * HW + hw;

    const float* xb = xin + (size_t)b * HW;
    float acc = 0.f;
#pragma unroll
    for (int d = 1; d <= 3; ++d) {
#pragma unroll
        for (int ki = 0; ki < 3; ++ki) {
            const int ii = i + (ki - 1) * d;
            const bool vi = (unsigned)ii < (unsigned)H_;
#pragma unroll
            for (int kj = 0; kj < 3; ++kj) {
                const int jj = j + (kj - 1) * d;
                float xv = 0.f;
                if (vi && (unsigned)jj < (unsigned)W_)
                    xv = xb[ii * W_ + jj];
                const int plane = (d - 1) * 9 + ki * 3 + kj;
                acc = fmaf(xv, (float)w[(size_t)plane * N + p], acc);
            }
        }
    }
    xout[p] = acc;
}

// ---------------------------------------------------------------------------
extern "C" void kernel_launch(void* const* d_in, const int* in_sizes, int n_in,
                              void* d_out, int out_size, void* d_ws, size_t ws_size,
                              hipStream_t stream)
{
    const float* g1   = (const float*)d_in[0];
    const float* g2   = (const float*)d_in[1];
    const float* g3   = (const float*)d_in[2];
    const float* fuse = (const float*)d_in[3];
    const float* x    = (const float*)d_in[4];
    float* out = (float*)d_out;

    char* ws = (char*)d_ws;
    _Float16* w = (_Float16*)ws;                    // 27*N*2 = 132.7 MB
    float* xa = (float*)(ws + (size_t)27 * N * 2);  // ping
    float* xb = xa + N;                             // pong

    const dim3 grid(W_ / 64, H_ / 4, B_);           // 10 x 120 x 8

    // Pass 1 fused with weight precompute (fp32 weights for this pass).
    wprep1_kernel<<<grid, 256, 0, stream>>>(g1, g2, g3, fuse, x, w, xa);

    // Passes 2..8 with fp16 weights. t=1..6 ping-pong, t=7 -> out.
    const float* src = xa;
    for (int t = 1; t < 8; ++t) {
        float* dst = (t == 7) ? out : ((t & 1) ? xb : xa);
        prop_kernel<<<grid, 256, 0, stream>>>(src, w, dst);
        src = dst;
    }
}